// Round 2
// baseline (158.951 us; speedup 1.0000x reference)
//
#include <hip/hip_runtime.h>
#include <stdint.h>
#include <stddef.h>

// Problem constants: B=4, T=2048, C=256, H=64, D=4
// rows = B*T = 8192 ; qkv row = 768 floats = [q(256)|k(256)|v(256)]
// q row layout (head,d) == (B,pos,head,d) which is what the attention wants.

// ---------------------------------------------------------------------------
// Host-side replication of np.random.default_rng(1234) op-list generation.
// SeedSequence(1234) -> PCG64 (XSL-RR 128/64) -> Generator.integers(4) via
// Lemire bounded uint32 ((u32*4)>>32; threshold==0 so no rejection), 32-bit
// draws come from pcg64's persistent half-buffer (low word first).
// NOTE: SeedSequence mix() is  L*x - R*y  (randutils seed_seq_fe), NOT xor.
// ---------------------------------------------------------------------------
static void compute_ops_host(int* kinds, int* wires) {
  const uint32_t MULT_A = 0x931e8875u;
  const uint32_t INIT_B = 0x8b51f9ddu, MULT_B = 0x58f38dedu;
  const uint32_t MIX_L = 0xca01f9ddu, MIX_R = 0x4973f715u;
  uint32_t hc = 0x43b0d7e5u; // INIT_A
  auto hashmix = [&](uint32_t v) -> uint32_t {
    v ^= hc; hc *= MULT_A; v *= hc; v ^= v >> 16; return v;
  };
  auto mix = [&](uint32_t x, uint32_t y) -> uint32_t {
    uint32_t r = (x * MIX_L) - (y * MIX_R); r ^= r >> 16; return r;
  };
  uint32_t pool[4];
  for (int i = 0; i < 4; ++i) pool[i] = hashmix(i == 0 ? 1234u : 0u);
  for (int s = 0; s < 4; ++s)
    for (int d = 0; d < 4; ++d)
      if (s != d) pool[d] = mix(pool[d], hashmix(pool[s]));
  uint32_t st32[8];
  uint32_t hcb = INIT_B;
  for (int i = 0; i < 8; ++i) {
    uint32_t dv = pool[i & 3];
    dv ^= hcb; hcb *= MULT_B; dv *= hcb; dv ^= dv >> 16;
    st32[i] = dv;
  }
  uint64_t s64[4];
  for (int k = 0; k < 4; ++k) s64[k] = (uint64_t)st32[2 * k] | ((uint64_t)st32[2 * k + 1] << 32);
  const __uint128_t M = ((__uint128_t)0x2360ed051fc65da4ULL << 64) | 0x4385df649fccf645ULL;
  __uint128_t initstate = ((__uint128_t)s64[0] << 64) | s64[1];
  __uint128_t inc = ((((__uint128_t)s64[2] << 64) | s64[3]) << 1) | (__uint128_t)1;
  __uint128_t state = inc;          // state=0; step -> state = inc
  state += initstate;
  state = state * M + inc;          // second seeding step
  bool has = false; uint32_t hbuf = 0;
  auto next32 = [&]() -> uint32_t {
    if (has) { has = false; return hbuf; }
    state = state * M + inc;
    uint64_t hi = (uint64_t)(state >> 64), lo = (uint64_t)state;
    uint64_t x = hi ^ lo;
    unsigned rot = (unsigned)(state >> 122) & 63u;
    uint64_t o = (x >> rot) | (x << ((64u - rot) & 63u));
    has = true; hbuf = (uint32_t)(o >> 32);
    return (uint32_t)o;
  };
  for (int i = 0; i < 20; ++i) {
    kinds[i] = (int)(((uint64_t)next32() * 4ull) >> 32); // 0=rx 1=ry 2=rz 3=cnot
    wires[i] = (int)(((uint64_t)next32() * 4ull) >> 32);
  }
}

// ---------------------------------------------------------------------------
// Build the fixed 16x16 unitary U = [prod_w RY_w(ry)RX_w(rx)] * G20...G1
// Wire w <-> bit (3-w) of the 4-bit state index (wire0 = MSB).
// 256 threads, 1 block; U stored as interleaved (re,im) pairs.
// ---------------------------------------------------------------------------
__global__ __launch_bounds__(256) void build_unitary(
    const float* __restrict__ rand_angles, const float* __restrict__ rx_theta,
    const float* __restrict__ ry_theta, unsigned long long kinds,
    unsigned long long wires, float* __restrict__ Uout)
{
  __shared__ float Ur[16][16], Ui[16][16];
  const int tid = threadIdx.x;
  {
    int i = tid >> 4, j = tid & 15;
    Ur[i][j] = (i == j) ? 1.0f : 0.0f;
    Ui[i][j] = 0.0f;
  }
  __syncthreads();
  for (int g = 0; g < 28; ++g) {
    int kind, w; float th;
    if (g < 20) {
      kind = (int)((kinds >> (2 * g)) & 3ull);
      w = (int)((wires >> (2 * g)) & 3ull);
      th = rand_angles[g];
    } else {
      int e = g - 20;           // rx then ry on each wire (commuting across wires)
      w = e >> 1;
      kind = (e & 1) ? 1 : 0;
      th = (e & 1) ? ry_theta[0] : rx_theta[0];
    }
    if (kind == 3) {
      // CNOT c=w, t=(w+1)%4 : row permutation i <-> i^mt for rows with c-bit set
      int mc = 8 >> w, mt = 8 >> ((w + 1) & 3);
      if (tid < 64) {
        int pi = tid >> 4, j = tid & 15;
        // enumerate rows with (i & mc)!=0 && (i & mt)==0 from the 2 free bits
        int i = mc, pbit = 0;
        for (int b = 3; b >= 0; --b) {
          int mask = 1 << b;
          if (mask != mc && mask != mt) { i |= ((pi >> pbit) & 1) << b; pbit++; }
        }
        int i2 = i | mt;
        float tr = Ur[i][j], ti = Ui[i][j];
        Ur[i][j] = Ur[i2][j]; Ui[i][j] = Ui[i2][j];
        Ur[i2][j] = tr; Ui[i2][j] = ti;
      }
    } else {
      float s, c;
      sincosf(th * 0.5f, &s, &c);
      float g00r, g00i, g01r, g01i, g10r, g10i, g11r, g11i;
      if (kind == 0) {        // RX: [[c,-is],[-is,c]]
        g00r = c; g00i = 0; g01r = 0; g01i = -s; g10r = 0; g10i = -s; g11r = c; g11i = 0;
      } else if (kind == 1) { // RY: [[c,-s],[s,c]]
        g00r = c; g00i = 0; g01r = -s; g01i = 0; g10r = s; g10i = 0; g11r = c; g11i = 0;
      } else {                // RZ: diag(c-is, c+is)
        g00r = c; g00i = -s; g01r = 0; g01i = 0; g10r = 0; g10i = 0; g11r = c; g11i = s;
      }
      if (tid < 128) {
        int p = tid >> 4, j = tid & 15;
        int mb = 3 - w;
        int i0 = ((p >> mb) << (mb + 1)) | (p & ((1 << mb) - 1));
        int i1 = i0 | (1 << mb);
        float ar = Ur[i0][j], ai = Ui[i0][j];
        float br = Ur[i1][j], bi = Ui[i1][j];
        Ur[i0][j] = g00r * ar - g00i * ai + g01r * br - g01i * bi;
        Ui[i0][j] = g00r * ai + g00i * ar + g01r * bi + g01i * br;
        Ur[i1][j] = g10r * ar - g10i * ai + g11r * br - g11i * bi;
        Ui[i1][j] = g10r * ai + g10i * ar + g11r * bi + g11i * br;
      }
    }
    __syncthreads();
  }
  Uout[2 * tid]     = Ur[tid >> 4][tid & 15];
  Uout[2 * tid + 1] = Ui[tid >> 4][tid & 15];
}

// ---------------------------------------------------------------------------
// fp32 GEMM: C[M,N] = A[M,K] @ B[N,K]^T (+bias). BM=BN=64, BK=32, 256 thr,
// 4x4 microtile. LDS stored K-major [32][68] (pad 68 keeps float4 reads
// 16B-aligned & conflict-light).
// ---------------------------------------------------------------------------
__global__ __launch_bounds__(256) void gemm_nt64(
    const float* __restrict__ A, const float* __restrict__ B,
    const float* __restrict__ bias, float* __restrict__ C,
    int M, int N, int K)
{
  __shared__ float As[32][68];
  __shared__ float Bs[32][68];
  const int bm = blockIdx.y * 64;
  const int bn = blockIdx.x * 64;
  const int tid = threadIdx.x;
  const int tx = tid & 15, ty = tid >> 4;
  float acc[4][4] = {};
  for (int k0 = 0; k0 < K; k0 += 32) {
#pragma unroll
    for (int i = 0; i < 2; ++i) {
      int idx = tid + i * 256;          // 0..511 float4 slots
      int r = idx >> 3;                 // tile row 0..63
      int c = (idx & 7) << 2;           // tile col 0,4,...,28
      float4 va = *reinterpret_cast<const float4*>(&A[(size_t)(bm + r) * K + (k0 + c)]);
      As[c + 0][r] = va.x; As[c + 1][r] = va.y; As[c + 2][r] = va.z; As[c + 3][r] = va.w;
      float4 vb = *reinterpret_cast<const float4*>(&B[(size_t)(bn + r) * K + (k0 + c)]);
      Bs[c + 0][r] = vb.x; Bs[c + 1][r] = vb.y; Bs[c + 2][r] = vb.z; Bs[c + 3][r] = vb.w;
    }
    __syncthreads();
#pragma unroll
    for (int kk = 0; kk < 32; ++kk) {
      float4 a = *reinterpret_cast<const float4*>(&As[kk][ty << 2]);
      float4 b = *reinterpret_cast<const float4*>(&Bs[kk][tx << 2]);
      acc[0][0] += a.x * b.x; acc[0][1] += a.x * b.y; acc[0][2] += a.x * b.z; acc[0][3] += a.x * b.w;
      acc[1][0] += a.y * b.x; acc[1][1] += a.y * b.y; acc[1][2] += a.y * b.z; acc[1][3] += a.y * b.w;
      acc[2][0] += a.z * b.x; acc[2][1] += a.z * b.y; acc[2][2] += a.z * b.z; acc[2][3] += a.z * b.w;
      acc[3][0] += a.w * b.x; acc[3][1] += a.w * b.y; acc[3][2] += a.w * b.z; acc[3][3] += a.w * b.w;
    }
    __syncthreads();
  }
  float4 bv = make_float4(0.f, 0.f, 0.f, 0.f);
  if (bias != nullptr) bv = *reinterpret_cast<const float4*>(&bias[bn + (tx << 2)]);
#pragma unroll
  for (int i = 0; i < 4; ++i) {
    size_t r = (size_t)(bm + (ty << 2) + i);
    float4 o = make_float4(acc[i][0] + bv.x, acc[i][1] + bv.y, acc[i][2] + bv.z, acc[i][3] + bv.w);
    *reinterpret_cast<float4*>(&C[r * N + bn + (tx << 2)]) = o;
  }
}

// ---------------------------------------------------------------------------
// Quantum transform, in-place on every 4-float vector of the qkv buffer.
// a[16] = product state from RY encoder (real); psi = U a ; z_w = sum ± |psi|^2
// ---------------------------------------------------------------------------
__global__ __launch_bounds__(256) void quantum_apply(
    float* __restrict__ buf, const float* __restrict__ U, int nvec)
{
  __shared__ float Ur[16][16], Ui[16][16];
  {
    int t = threadIdx.x;
    Ur[t >> 4][t & 15] = U[2 * t];
    Ui[t >> 4][t & 15] = U[2 * t + 1];
  }
  __syncthreads();
  int v = blockIdx.x * 256 + threadIdx.x;
  if (v >= nvec) return;
  float4 ang = *reinterpret_cast<const float4*>(&buf[(size_t)v * 4]);
  float c[4], s[4];
  sincosf(ang.x * 0.5f, &s[0], &c[0]);
  sincosf(ang.y * 0.5f, &s[1], &c[1]);
  sincosf(ang.z * 0.5f, &s[2], &c[2]);
  sincosf(ang.w * 0.5f, &s[3], &c[3]);
  float a[16];
#pragma unroll
  for (int j = 0; j < 16; ++j)
    a[j] = ((j & 8) ? s[0] : c[0]) * ((j & 4) ? s[1] : c[1]) *
           ((j & 2) ? s[2] : c[2]) * ((j & 1) ? s[3] : c[3]);
  float z0 = 0, z1 = 0, z2 = 0, z3 = 0;
#pragma unroll
  for (int i = 0; i < 16; ++i) {
    float re = 0, im = 0;
#pragma unroll
    for (int j = 0; j < 16; ++j) { re += Ur[i][j] * a[j]; im += Ui[i][j] * a[j]; }
    float p = re * re + im * im;
    z0 += (i & 8) ? -p : p;
    z1 += (i & 4) ? -p : p;
    z2 += (i & 2) ? -p : p;
    z3 += (i & 1) ? -p : p;
  }
  *reinterpret_cast<float4*>(&buf[(size_t)v * 4]) = make_float4(z0, z1, z2, z3);
}

// ---------------------------------------------------------------------------
// Attention across heads: per (b,pos): S = Q K^T / 2 (64x64), softmax rows,
// Y = A V (64x4). 4 waves/block = 4 positions; lane = row (head t).
// Writes y in (B, head, pos, d) layout == the reference's faithful reshape.
// ---------------------------------------------------------------------------
__global__ __launch_bounds__(256) void attn64(
    const float* __restrict__ qkv, float* __restrict__ y)
{
  __shared__ float Ksh[4][64][4];
  __shared__ float Vsh[4][64][4];
  const int wave = threadIdx.x >> 6, lane = threadIdx.x & 63;
  const int posIdx = blockIdx.x * 4 + wave;   // b*2048 + pos
  const float* row = qkv + (size_t)posIdx * 768;
  float4 q = *reinterpret_cast<const float4*>(&row[lane * 4]);
  *reinterpret_cast<float4*>(&Ksh[wave][lane][0]) =
      *reinterpret_cast<const float4*>(&row[256 + lane * 4]);
  *reinterpret_cast<float4*>(&Vsh[wave][lane][0]) =
      *reinterpret_cast<const float4*>(&row[512 + lane * 4]);
  __syncthreads();
  float sc[64];
  float mx = -3.4e38f;
#pragma unroll
  for (int ss = 0; ss < 64; ++ss) {
    float d = q.x * Ksh[wave][ss][0] + q.y * Ksh[wave][ss][1] +
              q.z * Ksh[wave][ss][2] + q.w * Ksh[wave][ss][3];
    d *= 0.5f;   // / sqrt(D=4)
    sc[ss] = d;
    mx = fmaxf(mx, d);
  }
  float sum = 0.f;
#pragma unroll
  for (int ss = 0; ss < 64; ++ss) { float e = __expf(sc[ss] - mx); sc[ss] = e; sum += e; }
  float inv = 1.f / sum;
  float ax = 0, ay = 0, az = 0, aw = 0;
#pragma unroll
  for (int ss = 0; ss < 64; ++ss) {
    float wgt = sc[ss] * inv;
    ax += wgt * Vsh[wave][ss][0]; ay += wgt * Vsh[wave][ss][1];
    az += wgt * Vsh[wave][ss][2]; aw += wgt * Vsh[wave][ss][3];
  }
  const int b = posIdx >> 11, pos = posIdx & 2047;
  *reinterpret_cast<float4*>(&y[(((size_t)(b * 64 + lane)) * 2048 + pos) * 4]) =
      make_float4(ax, ay, az, aw);
}

// ---------------------------------------------------------------------------
extern "C" void kernel_launch(void* const* d_in, const int* in_sizes, int n_in,
                              void* d_out, int out_size, void* d_ws, size_t ws_size,
                              hipStream_t stream)
{
  const float* x    = (const float*)d_in[0];
  const float* wqkv = (const float*)d_in[1];
  const float* wout = (const float*)d_in[2];
  const float* bout = (const float*)d_in[3];
  const float* rxth = (const float*)d_in[4];
  const float* ryth = (const float*)d_in[5];
  const float* rang = (const float*)d_in[6];
  float* out = (float*)d_out;

  float* U   = (float*)d_ws;                         // 512 floats
  float* qkv = (float*)d_ws + 1024;                  // 8192*768 floats
  float* y   = qkv + (size_t)8192 * 768;             // 8192*256 floats

  int kinds[20], wires[20];
  compute_ops_host(kinds, wires);
  unsigned long long pk = 0, pw = 0;
  for (int i = 0; i < 20; ++i) {
    pk |= (unsigned long long)(kinds[i] & 3) << (2 * i);
    pw |= (unsigned long long)(wires[i] & 3) << (2 * i);
  }

  hipLaunchKernelGGL(build_unitary, dim3(1), dim3(256), 0, stream,
                     rang, rxth, ryth, pk, pw, U);
  hipLaunchKernelGGL(gemm_nt64, dim3(768 / 64, 8192 / 64), dim3(256), 0, stream,
                     x, wqkv, (const float*)nullptr, qkv, 8192, 768, 256);
  hipLaunchKernelGGL(quantum_apply, dim3((8192 * 768 / 4) / 256), dim3(256), 0, stream,
                     qkv, U, 8192 * 768 / 4);
  hipLaunchKernelGGL(attn64, dim3(8192 / 4), dim3(256), 0, stream, qkv, y);
  hipLaunchKernelGGL(gemm_nt64, dim3(256 / 64, 8192 / 64), dim3(256), 0, stream,
                     y, wout, bout, out, 8192, 256, 256);
}

// Round 3
// 148.454 us; speedup vs baseline: 1.0707x; 1.0707x over previous
//
#include <hip/hip_runtime.h>
#include <stdint.h>
#include <stddef.h>

// Problem constants: B=4, T=2048, C=256, H=64, D=4
// rows = B*T = 8192 ; qkv row = 768 floats = [q(256)|k(256)|v(256)]

// ---------------------------------------------------------------------------
// Host-side replication of np.random.default_rng(1234) op-list generation.
// SeedSequence mix() is L*x - R*y (randutils seed_seq_fe). Verified (R2 pass).
// ---------------------------------------------------------------------------
static void compute_ops_host(int* kinds, int* wires) {
  const uint32_t MULT_A = 0x931e8875u;
  const uint32_t INIT_B = 0x8b51f9ddu, MULT_B = 0x58f38dedu;
  const uint32_t MIX_L = 0xca01f9ddu, MIX_R = 0x4973f715u;
  uint32_t hc = 0x43b0d7e5u; // INIT_A
  auto hashmix = [&](uint32_t v) -> uint32_t {
    v ^= hc; hc *= MULT_A; v *= hc; v ^= v >> 16; return v;
  };
  auto mix = [&](uint32_t x, uint32_t y) -> uint32_t {
    uint32_t r = (x * MIX_L) - (y * MIX_R); r ^= r >> 16; return r;
  };
  uint32_t pool[4];
  for (int i = 0; i < 4; ++i) pool[i] = hashmix(i == 0 ? 1234u : 0u);
  for (int s = 0; s < 4; ++s)
    for (int d = 0; d < 4; ++d)
      if (s != d) pool[d] = mix(pool[d], hashmix(pool[s]));
  uint32_t st32[8];
  uint32_t hcb = INIT_B;
  for (int i = 0; i < 8; ++i) {
    uint32_t dv = pool[i & 3];
    dv ^= hcb; hcb *= MULT_B; dv *= hcb; dv ^= dv >> 16;
    st32[i] = dv;
  }
  uint64_t s64[4];
  for (int k = 0; k < 4; ++k) s64[k] = (uint64_t)st32[2 * k] | ((uint64_t)st32[2 * k + 1] << 32);
  const __uint128_t M = ((__uint128_t)0x2360ed051fc65da4ULL << 64) | 0x4385df649fccf645ULL;
  __uint128_t initstate = ((__uint128_t)s64[0] << 64) | s64[1];
  __uint128_t inc = ((((__uint128_t)s64[2] << 64) | s64[3]) << 1) | (__uint128_t)1;
  __uint128_t state = inc;
  state += initstate;
  state = state * M + inc;
  bool has = false; uint32_t hbuf = 0;
  auto next32 = [&]() -> uint32_t {
    if (has) { has = false; return hbuf; }
    state = state * M + inc;
    uint64_t hi = (uint64_t)(state >> 64), lo = (uint64_t)state;
    uint64_t x = hi ^ lo;
    unsigned rot = (unsigned)(state >> 122) & 63u;
    uint64_t o = (x >> rot) | (x << ((64u - rot) & 63u));
    has = true; hbuf = (uint32_t)(o >> 32);
    return (uint32_t)o;
  };
  for (int i = 0; i < 20; ++i) {
    kinds[i] = (int)(((uint64_t)next32() * 4ull) >> 32); // 0=rx 1=ry 2=rz 3=cnot
    wires[i] = (int)(((uint64_t)next32() * 4ull) >> 32);
  }
}

// ---------------------------------------------------------------------------
// Build U (16x16 unitary), then M_w = Re(U^† D_w U), then the 3^4 tensors
// T[w][e1,e2,e3][e4] (e4 padded to 4) with z_w = sum T * prod_i t_i[e_i],
// t_i = (1, cos v_i, sin v_i).  One block, 256 threads, runs once.
// ---------------------------------------------------------------------------
__global__ __launch_bounds__(256) void build_tables(
    const float* __restrict__ rand_angles, const float* __restrict__ rx_theta,
    const float* __restrict__ ry_theta, unsigned long long kinds,
    unsigned long long wires, float* __restrict__ Tg)
{
  __shared__ float Ur[16][16], Ui[16][16];
  __shared__ float Msh[4][16][16];
  const int tid = threadIdx.x;
  {
    int i = tid >> 4, j = tid & 15;
    Ur[i][j] = (i == j) ? 1.0f : 0.0f;
    Ui[i][j] = 0.0f;
  }
  __syncthreads();
  for (int g = 0; g < 28; ++g) {
    int kind, w; float th;
    if (g < 20) {
      kind = (int)((kinds >> (2 * g)) & 3ull);
      w = (int)((wires >> (2 * g)) & 3ull);
      th = rand_angles[g];
    } else {
      int e = g - 20;
      w = e >> 1;
      kind = (e & 1) ? 1 : 0;
      th = (e & 1) ? ry_theta[0] : rx_theta[0];
    }
    if (kind == 3) {
      int mc = 8 >> w, mt = 8 >> ((w + 1) & 3);
      if (tid < 64) {
        int pi = tid >> 4, j = tid & 15;
        int i = mc, pbit = 0;
        for (int b = 3; b >= 0; --b) {
          int mask = 1 << b;
          if (mask != mc && mask != mt) { i |= ((pi >> pbit) & 1) << b; pbit++; }
        }
        int i2 = i | mt;
        float tr = Ur[i][j], ti = Ui[i][j];
        Ur[i][j] = Ur[i2][j]; Ui[i][j] = Ui[i2][j];
        Ur[i2][j] = tr; Ui[i2][j] = ti;
      }
    } else {
      float s, c;
      sincosf(th * 0.5f, &s, &c);
      float g00r, g00i, g01r, g01i, g10r, g10i, g11r, g11i;
      if (kind == 0) {        // RX
        g00r = c; g00i = 0; g01r = 0; g01i = -s; g10r = 0; g10i = -s; g11r = c; g11i = 0;
      } else if (kind == 1) { // RY
        g00r = c; g00i = 0; g01r = -s; g01i = 0; g10r = s; g10i = 0; g11r = c; g11i = 0;
      } else {                // RZ
        g00r = c; g00i = -s; g01r = 0; g01i = 0; g10r = 0; g10i = 0; g11r = c; g11i = s;
      }
      if (tid < 128) {
        int p = tid >> 4, j = tid & 15;
        int mb = 3 - w;
        int i0 = ((p >> mb) << (mb + 1)) | (p & ((1 << mb) - 1));
        int i1 = i0 | (1 << mb);
        float ar = Ur[i0][j], ai = Ui[i0][j];
        float br = Ur[i1][j], bi = Ui[i1][j];
        Ur[i0][j] = g00r * ar - g00i * ai + g01r * br - g01i * bi;
        Ui[i0][j] = g00r * ai + g00i * ar + g01r * bi + g01i * br;
        Ur[i1][j] = g10r * ar - g10i * ai + g11r * br - g11i * bi;
        Ui[i1][j] = g10r * ai + g10i * ar + g11r * bi + g11i * br;
      }
    }
    __syncthreads();
  }
  // Phase B: M_w[j][k] = sum_l sign_w(l) (Ur[l][j]Ur[l][k] + Ui[l][j]Ui[l][k])
  {
    int j = tid >> 4, k = tid & 15;
    float m0 = 0, m1 = 0, m2 = 0, m3 = 0;
#pragma unroll
    for (int l = 0; l < 16; ++l) {
      float p = Ur[l][j] * Ur[l][k] + Ui[l][j] * Ui[l][k];
      m0 += (l & 8) ? -p : p;
      m1 += (l & 4) ? -p : p;
      m2 += (l & 2) ? -p : p;
      m3 += (l & 1) ? -p : p;
    }
    Msh[0][j][k] = m0; Msh[1][j][k] = m1; Msh[2][j][k] = m2; Msh[3][j][k] = m3;
  }
  __syncthreads();
  // Phase C: T[w][r=(e1,e2,e3)][e4] = sum over the 16 nonzero (j,k) pairs
  if (tid < 81) {
    int e4 = tid % 3, r = tid / 3;
    int ee0 = r / 9, ee1 = (r / 3) % 3, ee2 = r % 3;
    int ee[4] = { ee0, ee1, ee2, e4 };
    float s0 = 0, s1 = 0, s2 = 0, s3 = 0;
    for (int m = 0; m < 16; ++m) {
      int j = 0, k = 0; float coef = 1.0f;
      for (int i = 0; i < 4; ++i) {
        int o = (m >> i) & 1;
        int e = ee[i];
        int bj, bk; float c;
        if (e == 2)      { bj = o; bk = 1 - o; c = 0.5f; }
        else if (e == 1) { bj = o; bk = o;     c = o ? -0.5f : 0.5f; }
        else             { bj = o; bk = o;     c = 0.5f; }
        j |= bj << (3 - i); k |= bk << (3 - i);
        coef *= c;
      }
      s0 += coef * Msh[0][j][k]; s1 += coef * Msh[1][j][k];
      s2 += coef * Msh[2][j][k]; s3 += coef * Msh[3][j][k];
    }
    Tg[(0 * 27 + r) * 4 + e4] = s0;
    Tg[(1 * 27 + r) * 4 + e4] = s1;
    Tg[(2 * 27 + r) * 4 + e4] = s2;
    Tg[(3 * 27 + r) * 4 + e4] = s3;
  }
  if (tid >= 81 && tid < 108) {   // zero the e4=3 pad
    int r = tid - 81;
    for (int w = 0; w < 4; ++w) Tg[(w * 27 + r) * 4 + 3] = 0.0f;
  }
}

// ---------------------------------------------------------------------------
// Quantum transform via tensor contraction; 4 vectors per thread (amortizes
// the broadcast T reads 4x). In-place on qkv.
// ---------------------------------------------------------------------------
__global__ __launch_bounds__(256) void quantum_apply4(
    float* __restrict__ buf, const float* __restrict__ Tg)
{
  __shared__ float Tsh[432];
  for (int i = threadIdx.x; i < 432; i += 256) Tsh[i] = Tg[i];
  __syncthreads();
  size_t base = ((size_t)blockIdx.x * 256 + threadIdx.x) * 16;
  float4 A0 = *reinterpret_cast<const float4*>(&buf[base]);
  float4 A1 = *reinterpret_cast<const float4*>(&buf[base + 4]);
  float4 A2 = *reinterpret_cast<const float4*>(&buf[base + 8]);
  float4 A3 = *reinterpret_cast<const float4*>(&buf[base + 12]);
  float ang[4][4] = {
    { A0.x, A0.y, A0.z, A0.w }, { A1.x, A1.y, A1.z, A1.w },
    { A2.x, A2.y, A2.z, A2.w }, { A3.x, A3.y, A3.z, A3.w } };
  float cv[4][4], sv[4][4];
#pragma unroll
  for (int v = 0; v < 4; ++v)
#pragma unroll
    for (int i = 0; i < 4; ++i)
      __sincosf(ang[v][i], &sv[v][i], &cv[v][i]);
  float z[4][4];
#pragma unroll
  for (int w = 0; w < 4; ++w) {
    float a1_[4] = { 0, 0, 0, 0 };
#pragma unroll
    for (int e1 = 0; e1 < 3; ++e1) {
      float a2_[4] = { 0, 0, 0, 0 };
#pragma unroll
      for (int e2 = 0; e2 < 3; ++e2) {
        float a3_[4] = { 0, 0, 0, 0 };
#pragma unroll
        for (int e3 = 0; e3 < 3; ++e3) {
          const float4 t4 = *reinterpret_cast<const float4*>(
              &Tsh[(w * 27 + e1 * 9 + e2 * 3 + e3) * 4]);
#pragma unroll
          for (int v = 0; v < 4; ++v) {
            float inner = fmaf(sv[v][3], t4.z, fmaf(cv[v][3], t4.y, t4.x));
            if (e3 == 0)      a3_[v] += inner;
            else if (e3 == 1) a3_[v] = fmaf(inner, cv[v][2], a3_[v]);
            else              a3_[v] = fmaf(inner, sv[v][2], a3_[v]);
          }
        }
#pragma unroll
        for (int v = 0; v < 4; ++v) {
          if (e2 == 0)      a2_[v] += a3_[v];
          else if (e2 == 1) a2_[v] = fmaf(a3_[v], cv[v][1], a2_[v]);
          else              a2_[v] = fmaf(a3_[v], sv[v][1], a2_[v]);
        }
      }
#pragma unroll
      for (int v = 0; v < 4; ++v) {
        if (e1 == 0)      a1_[v] += a2_[v];
        else if (e1 == 1) a1_[v] = fmaf(a2_[v], cv[v][0], a1_[v]);
        else              a1_[v] = fmaf(a2_[v], sv[v][0], a1_[v]);
      }
    }
#pragma unroll
    for (int v = 0; v < 4; ++v) z[v][w] = a1_[v];
  }
  *reinterpret_cast<float4*>(&buf[base])      = make_float4(z[0][0], z[0][1], z[0][2], z[0][3]);
  *reinterpret_cast<float4*>(&buf[base + 4])  = make_float4(z[1][0], z[1][1], z[1][2], z[1][3]);
  *reinterpret_cast<float4*>(&buf[base + 8])  = make_float4(z[2][0], z[2][1], z[2][2], z[2][3]);
  *reinterpret_cast<float4*>(&buf[base + 12]) = make_float4(z[3][0], z[3][1], z[3][2], z[3][3]);
}

// ---------------------------------------------------------------------------
// fp32 GEMM 128x128 tile, BK=16, 8x8 microtile with split 4-float groups
// (cols {tx*4, 64+tx*4}, rows {ty*4, 64+ty*4}) so LDS reads are 16B-stride
// across lanes (2-way bank aliasing = free). C = A[M,K] @ B[N,K]^T (+bias).
// ---------------------------------------------------------------------------
__global__ __launch_bounds__(256) void gemm_nt128(
    const float* __restrict__ A, const float* __restrict__ B,
    const float* __restrict__ bias, float* __restrict__ C,
    int M, int N, int K)
{
  __shared__ float As[16][136];
  __shared__ float Bs[16][136];
  const int bm = blockIdx.y * 128;
  const int bn = blockIdx.x * 128;
  const int tid = threadIdx.x;
  const int tx = tid & 15, ty = tid >> 4;
  float acc[8][8] = {};
  for (int k0 = 0; k0 < K; k0 += 16) {
#pragma unroll
    for (int i = 0; i < 2; ++i) {
      int idx = tid + i * 256;          // 512 float4 slots per tile
      int r = idx >> 2;                 // row 0..127
      int c = (idx & 3) << 2;           // col 0,4,8,12
      float4 va = *reinterpret_cast<const float4*>(&A[(size_t)(bm + r) * K + (k0 + c)]);
      As[c + 0][r] = va.x; As[c + 1][r] = va.y; As[c + 2][r] = va.z; As[c + 3][r] = va.w;
      float4 vb = *reinterpret_cast<const float4*>(&B[(size_t)(bn + r) * K + (k0 + c)]);
      Bs[c + 0][r] = vb.x; Bs[c + 1][r] = vb.y; Bs[c + 2][r] = vb.z; Bs[c + 3][r] = vb.w;
    }
    __syncthreads();
#pragma unroll
    for (int kk = 0; kk < 16; ++kk) {
      float4 a0 = *reinterpret_cast<const float4*>(&As[kk][ty << 2]);
      float4 a1 = *reinterpret_cast<const float4*>(&As[kk][64 + (ty << 2)]);
      float4 b0 = *reinterpret_cast<const float4*>(&Bs[kk][tx << 2]);
      float4 b1 = *reinterpret_cast<const float4*>(&Bs[kk][64 + (tx << 2)]);
      float av[8] = { a0.x, a0.y, a0.z, a0.w, a1.x, a1.y, a1.z, a1.w };
      float bv[8] = { b0.x, b0.y, b0.z, b0.w, b1.x, b1.y, b1.z, b1.w };
#pragma unroll
      for (int i = 0; i < 8; ++i)
#pragma unroll
        for (int j = 0; j < 8; ++j)
          acc[i][j] = fmaf(av[i], bv[j], acc[i][j]);
    }
    __syncthreads();
  }
  float4 bva = make_float4(0.f, 0.f, 0.f, 0.f), bvb = bva;
  if (bias != nullptr) {
    bva = *reinterpret_cast<const float4*>(&bias[bn + (tx << 2)]);
    bvb = *reinterpret_cast<const float4*>(&bias[bn + 64 + (tx << 2)]);
  }
#pragma unroll
  for (int i = 0; i < 8; ++i) {
    size_t r = (size_t)(bm + ((i < 4) ? ((ty << 2) + i) : (64 + (ty << 2) + i - 4)));
    float4 o0 = make_float4(acc[i][0] + bva.x, acc[i][1] + bva.y,
                            acc[i][2] + bva.z, acc[i][3] + bva.w);
    float4 o1 = make_float4(acc[i][4] + bvb.x, acc[i][5] + bvb.y,
                            acc[i][6] + bvb.z, acc[i][7] + bvb.w);
    *reinterpret_cast<float4*>(&C[r * N + bn + (tx << 2)]) = o0;
    *reinterpret_cast<float4*>(&C[r * N + bn + 64 + (tx << 2)]) = o1;
  }
}

// ---------------------------------------------------------------------------
// fp32 GEMM 64x64 tile (kept for the final projection, N=256 -> 512 blocks).
// ---------------------------------------------------------------------------
__global__ __launch_bounds__(256) void gemm_nt64(
    const float* __restrict__ A, const float* __restrict__ B,
    const float* __restrict__ bias, float* __restrict__ C,
    int M, int N, int K)
{
  __shared__ float As[32][68];
  __shared__ float Bs[32][68];
  const int bm = blockIdx.y * 64;
  const int bn = blockIdx.x * 64;
  const int tid = threadIdx.x;
  const int tx = tid & 15, ty = tid >> 4;
  float acc[4][4] = {};
  for (int k0 = 0; k0 < K; k0 += 32) {
#pragma unroll
    for (int i = 0; i < 2; ++i) {
      int idx = tid + i * 256;
      int r = idx >> 3;
      int c = (idx & 7) << 2;
      float4 va = *reinterpret_cast<const float4*>(&A[(size_t)(bm + r) * K + (k0 + c)]);
      As[c + 0][r] = va.x; As[c + 1][r] = va.y; As[c + 2][r] = va.z; As[c + 3][r] = va.w;
      float4 vb = *reinterpret_cast<const float4*>(&B[(size_t)(bn + r) * K + (k0 + c)]);
      Bs[c + 0][r] = vb.x; Bs[c + 1][r] = vb.y; Bs[c + 2][r] = vb.z; Bs[c + 3][r] = vb.w;
    }
    __syncthreads();
#pragma unroll
    for (int kk = 0; kk < 32; ++kk) {
      float4 a = *reinterpret_cast<const float4*>(&As[kk][ty << 2]);
      float4 b = *reinterpret_cast<const float4*>(&Bs[kk][tx << 2]);
      acc[0][0] += a.x * b.x; acc[0][1] += a.x * b.y; acc[0][2] += a.x * b.z; acc[0][3] += a.x * b.w;
      acc[1][0] += a.y * b.x; acc[1][1] += a.y * b.y; acc[1][2] += a.y * b.z; acc[1][3] += a.y * b.w;
      acc[2][0] += a.z * b.x; acc[2][1] += a.z * b.y; acc[2][2] += a.z * b.z; acc[2][3] += a.z * b.w;
      acc[3][0] += a.w * b.x; acc[3][1] += a.w * b.y; acc[3][2] += a.w * b.z; acc[3][3] += a.w * b.w;
    }
    __syncthreads();
  }
  float4 bv = make_float4(0.f, 0.f, 0.f, 0.f);
  if (bias != nullptr) bv = *reinterpret_cast<const float4*>(&bias[bn + (tx << 2)]);
#pragma unroll
  for (int i = 0; i < 4; ++i) {
    size_t r = (size_t)(bm + (ty << 2) + i);
    float4 o = make_float4(acc[i][0] + bv.x, acc[i][1] + bv.y, acc[i][2] + bv.z, acc[i][3] + bv.w);
    *reinterpret_cast<float4*>(&C[r * N + bn + (tx << 2)]) = o;
  }
}

// ---------------------------------------------------------------------------
// Attention across heads: per (b,pos): S = Q K^T / 2 (64x64), softmax rows,
// Y = A V. Writes y in (B, head, pos, d) layout (= reference's reshape).
// ---------------------------------------------------------------------------
__global__ __launch_bounds__(256) void attn64(
    const float* __restrict__ qkv, float* __restrict__ y)
{
  __shared__ float Ksh[4][64][4];
  __shared__ float Vsh[4][64][4];
  const int wave = threadIdx.x >> 6, lane = threadIdx.x & 63;
  const int posIdx = blockIdx.x * 4 + wave;   // b*2048 + pos
  const float* row = qkv + (size_t)posIdx * 768;
  float4 q = *reinterpret_cast<const float4*>(&row[lane * 4]);
  *reinterpret_cast<float4*>(&Ksh[wave][lane][0]) =
      *reinterpret_cast<const float4*>(&row[256 + lane * 4]);
  *reinterpret_cast<float4*>(&Vsh[wave][lane][0]) =
      *reinterpret_cast<const float4*>(&row[512 + lane * 4]);
  __syncthreads();
  float sc[64];
  float mx = -3.4e38f;
#pragma unroll
  for (int ss = 0; ss < 64; ++ss) {
    float d = q.x * Ksh[wave][ss][0] + q.y * Ksh[wave][ss][1] +
              q.z * Ksh[wave][ss][2] + q.w * Ksh[wave][ss][3];
    d *= 0.5f;
    sc[ss] = d;
    mx = fmaxf(mx, d);
  }
  float sum = 0.f;
#pragma unroll
  for (int ss = 0; ss < 64; ++ss) { float e = __expf(sc[ss] - mx); sc[ss] = e; sum += e; }
  float inv = 1.f / sum;
  float ax = 0, ay = 0, az = 0, aw = 0;
#pragma unroll
  for (int ss = 0; ss < 64; ++ss) {
    float wgt = sc[ss] * inv;
    ax += wgt * Vsh[wave][ss][0]; ay += wgt * Vsh[wave][ss][1];
    az += wgt * Vsh[wave][ss][2]; aw += wgt * Vsh[wave][ss][3];
  }
  const int b = posIdx >> 11, pos = posIdx & 2047;
  *reinterpret_cast<float4*>(&y[(((size_t)(b * 64 + lane)) * 2048 + pos) * 4]) =
      make_float4(ax, ay, az, aw);
}

// ---------------------------------------------------------------------------
extern "C" void kernel_launch(void* const* d_in, const int* in_sizes, int n_in,
                              void* d_out, int out_size, void* d_ws, size_t ws_size,
                              hipStream_t stream)
{
  const float* x    = (const float*)d_in[0];
  const float* wqkv = (const float*)d_in[1];
  const float* wout = (const float*)d_in[2];
  const float* bout = (const float*)d_in[3];
  const float* rxth = (const float*)d_in[4];
  const float* ryth = (const float*)d_in[5];
  const float* rang = (const float*)d_in[6];
  float* out = (float*)d_out;

  float* Tg  = (float*)d_ws;                         // 432 floats
  float* qkv = (float*)d_ws + 1024;                  // 8192*768 floats
  float* y   = qkv + (size_t)8192 * 768;             // 8192*256 floats

  int kinds[20], wires[20];
  compute_ops_host(kinds, wires);
  unsigned long long pk = 0, pw = 0;
  for (int i = 0; i < 20; ++i) {
    pk |= (unsigned long long)(kinds[i] & 3) << (2 * i);
    pw |= (unsigned long long)(wires[i] & 3) << (2 * i);
  }

  hipLaunchKernelGGL(build_tables, dim3(1), dim3(256), 0, stream,
                     rang, rxth, ryth, pk, pw, Tg);
  hipLaunchKernelGGL(gemm_nt128, dim3(768 / 128, 8192 / 128), dim3(256), 0, stream,
                     x, wqkv, (const float*)nullptr, qkv, 8192, 768, 256);
  hipLaunchKernelGGL(quantum_apply4, dim3(8192 * 768 / 4 / 4 / 256), dim3(256), 0, stream,
                     qkv, Tg);
  hipLaunchKernelGGL(attn64, dim3(8192 / 4), dim3(256), 0, stream, qkv, y);
  hipLaunchKernelGGL(gemm_nt64, dim3(256 / 64, 8192 / 64), dim3(256), 0, stream,
                     y, wout, bout, out, 8192, 256, 256);
}